// Round 9
// baseline (458.385 us; speedup 1.0000x reference)
//
#include <hip/hip_runtime.h>
#include <stdint.h>

typedef unsigned short u16;
typedef __attribute__((ext_vector_type(8))) short bf16x8;
typedef __attribute__((ext_vector_type(4))) short s16x4;
typedef __attribute__((ext_vector_type(4))) float f32x4;

#define MFMA16(a,b,c) __builtin_amdgcn_mfma_f32_16x16x32_bf16((a),(b),(c),0,0,0)

__device__ __forceinline__ u16 f2bf(float f) {
  union { float f; uint32_t u; } v; v.f = f;
  return (u16)((v.u + 0x7fffu + ((v.u >> 16) & 1u)) >> 16);
}

// async 16B global->LDS (lds dest = wave-uniform base + lane*16)
__device__ __forceinline__ void gload16(const void* g, void* l) {
  __builtin_amdgcn_global_load_lds((const __attribute__((address_space(1))) void*)g,
                                   (__attribute__((address_space(3))) void*)l, 16, 0, 0);
}

// Stage a 128x64 bf16 tile into lds[128*64] with chunk-xor swizzle.
// Physical chunk (r, pc) holds logical chunk (r, pc^(r&7)).
__device__ __forceinline__ void stage256(const u16* src, size_t stride, u16* lds, int tid) {
#pragma unroll
  for (int i = 0; i < 4; ++i) {
    const int L = i * 256 + tid;       // chunk 0..1023
    const int r = L >> 3, pc = L & 7;
    const int lc = pc ^ (r & 7);
    gload16(src + (size_t)r * stride + lc * 8, lds + (size_t)(i * 256 + (tid & ~63)) * 8);
  }
}
__device__ __forceinline__ void stage512(const u16* src, size_t stride, u16* lds, int tid) {
#pragma unroll
  for (int i = 0; i < 2; ++i) {
    const int L = i * 512 + tid;
    const int r = L >> 3, pc = L & 7;
    const int lc = pc ^ (r & 7);
    gload16(src + (size_t)r * stride + lc * 8, lds + (size_t)(i * 512 + (tid & ~63)) * 8);
  }
}
// read logical chunk kc of row from a swizzled (rows x 64) tile
#define TILE_AT(lds, row, kc) \
  (*(const bf16x8*)&(lds)[((((row) << 3) + ((kc) ^ ((row) & 7)))) << 3])

// ---------- kernel 1: cast hidden_states fp32 -> bf16 ----------
__global__ void k_cast(const float* __restrict__ src, u16* __restrict__ dst, int n8) {
  int idx = blockIdx.x * 256 + threadIdx.x;
  if (idx >= n8) return;
  const float4* s = (const float4*)src + (size_t)idx * 2;
  float4 a = s[0], b = s[1];
  bf16x8 o;
  o[0] = (short)f2bf(a.x); o[1] = (short)f2bf(a.y);
  o[2] = (short)f2bf(a.z); o[3] = (short)f2bf(a.w);
  o[4] = (short)f2bf(b.x); o[5] = (short)f2bf(b.y);
  o[6] = (short)f2bf(b.z); o[7] = (short)f2bf(b.w);
  *(bf16x8*)(dst + (size_t)idx * 8) = o;
}

// ---------- kernel 2: transpose+cast all 3 weights in one launch ----------
__global__ void k_wtrans3(const float* __restrict__ Wq, const float* __restrict__ Wk,
                          const float* __restrict__ Wv, u16* __restrict__ Wt0) {
  __shared__ u16 tile[32][33];
  const int widx = blockIdx.x >> 10;
  const float* W = (widx == 0) ? Wq : ((widx == 1) ? Wk : Wv);
  u16* Wt = Wt0 + (size_t)widx * 1048576;
  const int bid = blockIdx.x & 1023;
  int bd = bid >> 5, bj = bid & 31;
  int tx = threadIdx.x & 31, ty = threadIdx.x >> 5;
#pragma unroll
  for (int i = 0; i < 32; i += 8)
    tile[ty + i][tx] = f2bf(W[(size_t)(bd * 32 + ty + i) * 1024 + bj * 32 + tx]);
  __syncthreads();
#pragma unroll
  for (int i = 0; i < 32; i += 8)
    Wt[(size_t)(bj * 32 + ty + i) * 1024 + bd * 32 + tx] = tile[tx][ty + i];
}

// ---------- kernel 4: fused QKV GEMM (r1 form: single-buffer, 2 barriers/kb) ----------
__global__ __launch_bounds__(256, 2) void k_qkv(
    const u16* __restrict__ hsb, const u16* __restrict__ Wt,
    const float* __restrict__ bq, const float* __restrict__ bk, const float* __restrict__ bv,
    u16* __restrict__ Qb, u16* __restrict__ Kb, u16* __restrict__ Vt) {
  __shared__ u16 a_lds[128 * 64];
  __shared__ u16 b_lds[128 * 64];
  const int tid = threadIdx.x;
  const int lane = tid & 63, wid = tid >> 6;
  const int l15 = lane & 15, quad = lane >> 4;
  const int wr = wid >> 1, wc = wid & 1;
  const int bx = blockIdx.x & 31;
  const int by = blockIdx.x >> 5;
  const int Mbase = bx * 128;
  const int widx = by >> 3;               // 0=Q 1=K 2=V
  const int Nloc = (by & 7) * 128;

  f32x4 acc[4][4];
#pragma unroll
  for (int i = 0; i < 4; ++i)
#pragma unroll
    for (int j = 0; j < 4; ++j) acc[i][j] = (f32x4){0.f, 0.f, 0.f, 0.f};

  const u16* asrc = hsb + (size_t)Mbase * 1024;
  const u16* bsrc = Wt + (size_t)widx * 1048576 + (size_t)Nloc * 1024;

  for (int kb = 0; kb < 16; ++kb) {
    __syncthreads();
    stage256(asrc + kb * 64, 1024, a_lds, tid);
    stage256(bsrc + kb * 64, 1024, b_lds, tid);
    __syncthreads();
#pragma unroll
    for (int ks = 0; ks < 2; ++ks) {
      const int kc = ks * 4 + quad;
      bf16x8 af[4], bfr[4];
#pragma unroll
      for (int mt = 0; mt < 4; ++mt) af[mt] = TILE_AT(a_lds, wr * 64 + mt * 16 + l15, kc);
#pragma unroll
      for (int nt = 0; nt < 4; ++nt) bfr[nt] = TILE_AT(b_lds, wc * 64 + nt * 16 + l15, kc);
#pragma unroll
      for (int mt = 0; mt < 4; ++mt)
#pragma unroll
        for (int nt = 0; nt < 4; ++nt)
          acc[mt][nt] = MFMA16(af[mt], bfr[nt], acc[mt][nt]);
    }
  }
  const float* bias = (widx == 0) ? bq : ((widx == 1) ? bk : bv);
#pragma unroll
  for (int nt = 0; nt < 4; ++nt) {
    const int jloc = Nloc + wc * 64 + nt * 16 + l15;
    const float bias_v = bias[jloc];
#pragma unroll
    for (int mt = 0; mt < 4; ++mt) {
      const int Mr0 = Mbase + wr * 64 + mt * 16 + quad * 4;
      if (widx == 2) {
        const int b = Mr0 >> 11, mseq = Mr0 & 2047;
        const int g = jloc >> 7, h = jloc & 127;
        s16x4 pk;
#pragma unroll
        for (int r = 0; r < 4; ++r) pk[r] = (short)f2bf(acc[mt][nt][r] + bias_v);
        *(s16x4*)(Vt + (((size_t)b * 8 + g) * 128 + h) * 2048 + mseq) = pk;
      } else {
        u16* dst = (widx == 0) ? Qb : Kb;
#pragma unroll
        for (int r = 0; r < 4; ++r)
          dst[(size_t)(Mr0 + r) * 1024 + jloc] = f2bf(acc[mt][nt][r] + bias_v);
      }
    }
  }
}

// ---------- kernel 5: scores + softmax-over-g -> Pt ----------
// r8 structure (1 block/CU, XCD-pinned mt, nf=4, 3-deep kf ring) with an
// OPTIONAL internal mh loop: the Q tile is mh-independent, so when the
// workspace can hold both Pt halves (mclw=16) we stage Q once and compute
// both m-halves in one dispatch (halves Q-staging + one launch).
// Pt layout: [b][g][mcl][n][128m], mcl = mh*8+mt (merged) or mt (fallback).
__global__ __launch_bounds__(512, 2) void k_score(
    const u16* __restrict__ Qb, const u16* __restrict__ Kb,
    u16* __restrict__ Pt, int mh0, int nmh, int mclw) {
  __shared__ u16 q_lds[64 * 1024];  // 128 KB, 16B chunks xor-swizzled by (row&7)
  const int tid = threadIdx.x;
  const int w = tid >> 6;
  const int lane = tid & 63;
  const int l15 = lane & 15, quad = lane >> 4;
  const int bx = blockIdx.x;
  const int mt = bx & 7;                 // XCD-pinned m-chunk (128 m rows)
  const int nt = (bx >> 3) & 31;
  const int bcoord = bx >> 8;
  const int nbase = nt * 64;
  const size_t boff = (size_t)bcoord * 2048;

  // stage Q tile 64 x 1024 (8192 16B-chunks, 16 per thread), swizzled source
#pragma unroll
  for (int i = 0; i < 16; ++i) {
    const int idx = i * 512 + tid;
    const int r = idx >> 7, pc = idx & 127;
    const int lc = pc ^ (r & 7);
    gload16(Qb + (boff + nbase + r) * 1024 + lc * 8,
            q_lds + (size_t)(i * 512 + (tid & ~63)) * 8);
  }
  __syncthreads();

  const int mloc = w * 16 + quad * 4;

#pragma unroll 1
  for (int mh = mh0; mh < mh0 + nmh; ++mh) {
    f32x4 sacc[4][8];
#pragma unroll
    for (int nf = 0; nf < 4; ++nf)
#pragma unroll
      for (int g = 0; g < 8; ++g) sacc[nf][g] = (f32x4){0.f, 0.f, 0.f, 0.f};

    const u16* kp = Kb + (boff + mh * 1024 + mt * 128 + w * 16 + l15) * 1024 + quad * 8;

    // 3-deep K-fragment ring: load g and g+1 up front, prefetch g+2 each iter.
    bf16x8 kf[3][4];
#pragma unroll
    for (int ks = 0; ks < 4; ++ks) kf[0][ks] = *(const bf16x8*)(kp + 0 * 128 + ks * 32);
#pragma unroll
    for (int ks = 0; ks < 4; ++ks) kf[1][ks] = *(const bf16x8*)(kp + 1 * 128 + ks * 32);

#pragma unroll
    for (int g = 0; g < 8; ++g) {
      if (g < 6) {
#pragma unroll
        for (int ks = 0; ks < 4; ++ks)
          kf[(g + 2) % 3][ks] = *(const bf16x8*)(kp + (g + 2) * 128 + ks * 32);
      }
      __builtin_amdgcn_s_setprio(1);
#pragma unroll
      for (int ks = 0; ks < 4; ++ks) {
        const int kc = g * 16 + ks * 4 + quad;   // logical h-chunk
#pragma unroll
        for (int nf = 0; nf < 4; ++nf) {
          const int row = nf * 16 + l15;
          bf16x8 qf = *(const bf16x8*)&q_lds[row * 1024 + ((kc ^ (row & 7)) << 3)];
          sacc[nf][g] = MFMA16(kf[g % 3][ks], qf, sacc[nf][g]);  // D[m][n]
        }
      }
      __builtin_amdgcn_s_setprio(0);
    }
    // softmax over g (register-local)
#pragma unroll
    for (int nf = 0; nf < 4; ++nf)
#pragma unroll
      for (int r = 0; r < 4; ++r) {
        float s[8];
#pragma unroll
        for (int g = 0; g < 8; ++g) s[g] = sacc[nf][g][r] * 0.03125f;
        float mx = s[0];
#pragma unroll
        for (int g = 1; g < 8; ++g) mx = fmaxf(mx, s[g]);
        float sum = 0.f;
#pragma unroll
        for (int g = 0; g < 8; ++g) { s[g] = __expf(s[g] - mx); sum += s[g]; }
        const float rs = 1.0f / sum;
#pragma unroll
        for (int g = 0; g < 8; ++g) sacc[nf][g][r] = s[g] * rs;
      }
    // store Pt[b][g][mcl][n][128m], m contiguous per lane (s16x4 along m)
    const int mcl = (mclw == 16) ? (mh * 8 + mt) : mt;
#pragma unroll
    for (int g = 0; g < 8; ++g) {
      const size_t gm = ((size_t)(bcoord * 8 + g) * mclw + mcl) * 2048;
#pragma unroll
      for (int nf = 0; nf < 4; ++nf) {
        s16x4 pk;
#pragma unroll
        for (int r = 0; r < 4; ++r) pk[r] = (short)f2bf(sacc[nf][g][r]);
        *(s16x4*)(Pt + (gm + (size_t)(nbase + nf * 16 + l15)) * 128 + mloc) = pk;
      }
    }
  }
}

// ---------- kernel 6: PV GEMM (r1 form: 24 KB single buffer, no atomics) ----------
// grid 512 = 8g (XCD-pinned) x 32mt x 2b; 8 waves (2wr x 4wc); tile 64n x 128h.
// Merged mode (nmh=2): kb 0..31 covers the full K=2048, out plain-stored once
// (no 16 MB read-modify-write pass). Fallback: per-mh, mh1 load-add-store.
__global__ __launch_bounds__(512, 4) void k_pv(
    const u16* __restrict__ Pt, const u16* __restrict__ Vt,
    float* __restrict__ out, int mh0, int nmh, int mclw) {
  __shared__ u16 a_lds[64 * 64];
  __shared__ u16 b_lds[128 * 64];
  const int tid = threadIdx.x;
  const int lane = tid & 63, wid = tid >> 6;
  const int l15 = lane & 15, quad = lane >> 4;
  const int wr = wid >> 2, wc = wid & 3;
  const int bx = blockIdx.x;
  const int g = bx & 7;
  const int mt = (bx >> 3) & 31;
  const int bcoord = bx >> 8;
  const int nbase = mt * 64;
  const int nkb = nmh * 16;

  const u16* asrc = Pt + ((size_t)(bcoord * 8 + g) * mclw * 2048 + nbase) * 128;
  const u16* bsrc = Vt + (size_t)(bcoord * 8 + g) * 128 * 2048 + mh0 * 1024;

  f32x4 acc[2][2];
#pragma unroll
  for (int i = 0; i < 2; ++i)
#pragma unroll
    for (int j = 0; j < 2; ++j) acc[i][j] = (f32x4){0.f, 0.f, 0.f, 0.f};

  for (int kb = 0; kb < nkb; ++kb) {
    __syncthreads();
    {  // stage A 64x64 (512 chunks, 1 per thread)
      const int r = tid >> 3, pc = tid & 7;
      const int lc = pc ^ (r & 7);
      gload16(asrc + ((size_t)(kb >> 1) * 2048 + r) * 128 + (kb & 1) * 64 + lc * 8,
              a_lds + (size_t)(tid & ~63) * 8);
    }
    stage512(bsrc + kb * 64, 2048, b_lds, tid);
    __syncthreads();
#pragma unroll
    for (int ks = 0; ks < 2; ++ks) {
      const int kc = ks * 4 + quad;
      bf16x8 af[2], bfr[2];
#pragma unroll
      for (int mf = 0; mf < 2; ++mf) af[mf] = TILE_AT(a_lds, wr * 32 + mf * 16 + l15, kc);
#pragma unroll
      for (int nf = 0; nf < 2; ++nf) bfr[nf] = TILE_AT(b_lds, wc * 32 + nf * 16 + l15, kc);
#pragma unroll
      for (int mf = 0; mf < 2; ++mf)
#pragma unroll
        for (int nf = 0; nf < 2; ++nf)
          acc[mf][nf] = MFMA16(af[mf], bfr[nf], acc[mf][nf]);
    }
  }
  const bool first = (mh0 == 0);
#pragma unroll
  for (int mf = 0; mf < 2; ++mf)
#pragma unroll
    for (int nf = 0; nf < 2; ++nf)
#pragma unroll
      for (int r = 0; r < 4; ++r) {
        const int nrow = nbase + wr * 32 + mf * 16 + quad * 4 + r;
        const int col = g * 128 + wc * 32 + nf * 16 + l15;
        float* p = out + ((size_t)bcoord * 2048 + nrow) * 1024 + col;
        if (first) *p = acc[mf][nf][r];
        else       *p += acc[mf][nf][r];
      }
}

extern "C" void kernel_launch(void* const* d_in, const int* in_sizes, int n_in,
                              void* d_out, int out_size, void* d_ws, size_t ws_size,
                              hipStream_t stream) {
  const float* hs = (const float*)d_in[0];
  const float* Wq = (const float*)d_in[1];
  const float* bq = (const float*)d_in[2];
  const float* Wk = (const float*)d_in[3];
  const float* bk = (const float*)d_in[4];
  const float* Wv = (const float*)d_in[5];
  const float* bv = (const float*)d_in[6];
  float* out = (float*)d_out;

  u16* ws = (u16*)d_ws;
  u16* hsb = ws;                   // 4096x1024
  u16* Wt  = ws + 4194304;         // 3 x 1024x1024 (j-major)
  u16* Qb  = ws + 7340032;         // [b][n][1024]
  u16* Kb  = ws + 11534336;        // [b][m][1024]
  u16* Vt  = ws + 15728640;        // [b][g][h][m] = [2][8][128][2048]
  u16* Pt  = ws + 19922944;        // [b][g][mcl][n][128m]

  k_cast<<<2048, 256, 0, stream>>>(hs, hsb, 524288);
  k_wtrans3<<<3072, 256, 0, stream>>>(Wq, Wk, Wv, Wt);
  k_qkv<<<32 * 24, 256, 0, stream>>>(hsb, Wt, bq, bk, bv, Qb, Kb, Vt);

  // merged path needs Pt = [2][8][16][2048][128] u16 = 134 MB
  const size_t need_bytes = ((size_t)19922944 + 67108864) * 2;
  if (ws_size >= need_bytes) {
    k_score<<<512, 512, 0, stream>>>(Qb, Kb, Pt, 0, 2, 16);
    k_pv<<<512, 512, 0, stream>>>(Pt, Vt, out, 0, 2, 16);
  } else {
    for (int mh = 0; mh < 2; ++mh) {
      k_score<<<512, 512, 0, stream>>>(Qb, Kb, Pt, mh, 1, 8);
      k_pv<<<512, 512, 0, stream>>>(Pt, Vt, out, mh, 1, 8);
    }
  }
}

// Round 10
// 342.292 us; speedup vs baseline: 1.3392x; 1.3392x over previous
//
#include <hip/hip_runtime.h>
#include <stdint.h>

typedef unsigned short u16;
typedef __attribute__((ext_vector_type(8))) short bf16x8;
typedef __attribute__((ext_vector_type(4))) short s16x4;
typedef __attribute__((ext_vector_type(4))) float f32x4;

#define MFMA16(a,b,c) __builtin_amdgcn_mfma_f32_16x16x32_bf16((a),(b),(c),0,0,0)

__device__ __forceinline__ u16 f2bf(float f) {
  union { float f; uint32_t u; } v; v.f = f;
  return (u16)((v.u + 0x7fffu + ((v.u >> 16) & 1u)) >> 16);
}

// async 16B global->LDS (lds dest = wave-uniform base + lane*16)
__device__ __forceinline__ void gload16(const void* g, void* l) {
  __builtin_amdgcn_global_load_lds((const __attribute__((address_space(1))) void*)g,
                                   (__attribute__((address_space(3))) void*)l, 16, 0, 0);
}
// non-temporal variant (aux=2 -> NT cpol bit): bypass L2 allocation for
// streamed, reuse-free data so the reused operands (K / Vt slices) stay hot.
__device__ __forceinline__ void gload16nt(const void* g, void* l) {
  __builtin_amdgcn_global_load_lds((const __attribute__((address_space(1))) void*)g,
                                   (__attribute__((address_space(3))) void*)l, 16, 0, 2);
}

// Stage a 128x64 bf16 tile into lds[128*64] with chunk-xor swizzle.
// Physical chunk (r, pc) holds logical chunk (r, pc^(r&7)).
__device__ __forceinline__ void stage256(const u16* src, size_t stride, u16* lds, int tid) {
#pragma unroll
  for (int i = 0; i < 4; ++i) {
    const int L = i * 256 + tid;       // chunk 0..1023
    const int r = L >> 3, pc = L & 7;
    const int lc = pc ^ (r & 7);
    gload16(src + (size_t)r * stride + lc * 8, lds + (size_t)(i * 256 + (tid & ~63)) * 8);
  }
}
__device__ __forceinline__ void stage512(const u16* src, size_t stride, u16* lds, int tid) {
#pragma unroll
  for (int i = 0; i < 2; ++i) {
    const int L = i * 512 + tid;
    const int r = L >> 3, pc = L & 7;
    const int lc = pc ^ (r & 7);
    gload16(src + (size_t)r * stride + lc * 8, lds + (size_t)(i * 512 + (tid & ~63)) * 8);
  }
}
// read logical chunk kc of row from a swizzled (rows x 64) tile
#define TILE_AT(lds, row, kc) \
  (*(const bf16x8*)&(lds)[((((row) << 3) + ((kc) ^ ((row) & 7)))) << 3])

// ---------- kernel 1: prep = cast hidden_states + transpose 3 weights ----------
__global__ void k_prep(const float* __restrict__ hs, u16* __restrict__ hsb,
                       const float* __restrict__ Wq, const float* __restrict__ Wk,
                       const float* __restrict__ Wv, u16* __restrict__ Wt0) {
  __shared__ u16 tile[32][33];
  const int bx = blockIdx.x;
  if (bx < 2048) {
    const int idx = bx * 256 + threadIdx.x;      // exactly 524288 chunks
    const float4* s = (const float4*)hs + (size_t)idx * 2;
    float4 a = s[0], b = s[1];
    bf16x8 o;
    o[0] = (short)f2bf(a.x); o[1] = (short)f2bf(a.y);
    o[2] = (short)f2bf(a.z); o[3] = (short)f2bf(a.w);
    o[4] = (short)f2bf(b.x); o[5] = (short)f2bf(b.y);
    o[6] = (short)f2bf(b.z); o[7] = (short)f2bf(b.w);
    *(bf16x8*)(hsb + (size_t)idx * 8) = o;
    return;
  }
  const int bb = bx - 2048;
  const int widx = bb >> 10;
  const float* W = (widx == 0) ? Wq : ((widx == 1) ? Wk : Wv);
  u16* Wt = Wt0 + (size_t)widx * 1048576;
  const int bid = bb & 1023;
  int bd = bid >> 5, bj = bid & 31;
  int tx = threadIdx.x & 31, ty = threadIdx.x >> 5;
#pragma unroll
  for (int i = 0; i < 32; i += 8)
    tile[ty + i][tx] = f2bf(W[(size_t)(bd * 32 + ty + i) * 1024 + bj * 32 + tx]);
  __syncthreads();
#pragma unroll
  for (int i = 0; i < 32; i += 8)
    Wt[(size_t)(bj * 32 + ty + i) * 1024 + bd * 32 + tx] = tile[tx][ty + i];
}

// ---------- kernel 4: fused QKV GEMM (r1 form: single-buffer, 2 barriers/kb) ----------
__global__ __launch_bounds__(256, 2) void k_qkv(
    const u16* __restrict__ hsb, const u16* __restrict__ Wt,
    const float* __restrict__ bq, const float* __restrict__ bk, const float* __restrict__ bv,
    u16* __restrict__ Qb, u16* __restrict__ Kb, u16* __restrict__ Vt) {
  __shared__ u16 a_lds[128 * 64];
  __shared__ u16 b_lds[128 * 64];
  const int tid = threadIdx.x;
  const int lane = tid & 63, wid = tid >> 6;
  const int l15 = lane & 15, quad = lane >> 4;
  const int wr = wid >> 1, wc = wid & 1;
  const int bx = blockIdx.x & 31;
  const int by = blockIdx.x >> 5;
  const int Mbase = bx * 128;
  const int widx = by >> 3;               // 0=Q 1=K 2=V
  const int Nloc = (by & 7) * 128;

  f32x4 acc[4][4];
#pragma unroll
  for (int i = 0; i < 4; ++i)
#pragma unroll
    for (int j = 0; j < 4; ++j) acc[i][j] = (f32x4){0.f, 0.f, 0.f, 0.f};

  const u16* asrc = hsb + (size_t)Mbase * 1024;
  const u16* bsrc = Wt + (size_t)widx * 1048576 + (size_t)Nloc * 1024;

  for (int kb = 0; kb < 16; ++kb) {
    __syncthreads();
    stage256(asrc + kb * 64, 1024, a_lds, tid);
    stage256(bsrc + kb * 64, 1024, b_lds, tid);
    __syncthreads();
#pragma unroll
    for (int ks = 0; ks < 2; ++ks) {
      const int kc = ks * 4 + quad;
      bf16x8 af[4], bfr[4];
#pragma unroll
      for (int mt = 0; mt < 4; ++mt) af[mt] = TILE_AT(a_lds, wr * 64 + mt * 16 + l15, kc);
#pragma unroll
      for (int nt = 0; nt < 4; ++nt) bfr[nt] = TILE_AT(b_lds, wc * 64 + nt * 16 + l15, kc);
#pragma unroll
      for (int mt = 0; mt < 4; ++mt)
#pragma unroll
        for (int nt = 0; nt < 4; ++nt)
          acc[mt][nt] = MFMA16(af[mt], bfr[nt], acc[mt][nt]);
    }
  }
  const float* bias = (widx == 0) ? bq : ((widx == 1) ? bk : bv);
#pragma unroll
  for (int nt = 0; nt < 4; ++nt) {
    const int jloc = Nloc + wc * 64 + nt * 16 + l15;
    const float bias_v = bias[jloc];
#pragma unroll
    for (int mt = 0; mt < 4; ++mt) {
      const int Mr0 = Mbase + wr * 64 + mt * 16 + quad * 4;
      if (widx == 2) {
        const int b = Mr0 >> 11, mseq = Mr0 & 2047;
        const int g = jloc >> 7, h = jloc & 127;
        s16x4 pk;
#pragma unroll
        for (int r = 0; r < 4; ++r) pk[r] = (short)f2bf(acc[mt][nt][r] + bias_v);
        *(s16x4*)(Vt + (((size_t)b * 8 + g) * 128 + h) * 2048 + mseq) = pk;
      } else {
        u16* dst = (widx == 0) ? Qb : Kb;
#pragma unroll
        for (int r = 0; r < 4; ++r)
          dst[(size_t)(Mr0 + r) * 1024 + jloc] = f2bf(acc[mt][nt][r] + bias_v);
      }
    }
  }
}

// ---------- kernel 5: scores + softmax-over-g -> Pt[b][g][mt][n][128m] ----------
// r8 structure EXACTLY (1 block/CU, XCD-pinned mt, nf=4, 3-deep kf ring;
// every occupancy/merge attempt fell off the L2 ledge: r2/r6/r9).
// NEW: Q staging and Pt stores are non-temporal -- zero intra-XCD reuse,
// so they no longer flow through L2; the per-XCD 256 KB K slice keeps it.
__global__ __launch_bounds__(512, 2) void k_score(
    const u16* __restrict__ Qb, const u16* __restrict__ Kb,
    u16* __restrict__ Pt, int mh) {
  __shared__ u16 q_lds[64 * 1024];  // 128 KB, 16B chunks xor-swizzled by (row&7)
  const int tid = threadIdx.x;
  const int w = tid >> 6;
  const int lane = tid & 63;
  const int l15 = lane & 15, quad = lane >> 4;
  const int bx = blockIdx.x;
  const int mt = bx & 7;                 // XCD-pinned m-chunk (128 m rows)
  const int nt = (bx >> 3) & 31;
  const int bcoord = bx >> 8;
  const int nbase = nt * 64;
  const size_t boff = (size_t)bcoord * 2048;

  // stage Q tile 64 x 1024 (8192 16B-chunks, 16 per thread), swizzled source, NT
#pragma unroll
  for (int i = 0; i < 16; ++i) {
    const int idx = i * 512 + tid;
    const int r = idx >> 7, pc = idx & 127;
    const int lc = pc ^ (r & 7);
    gload16nt(Qb + (boff + nbase + r) * 1024 + lc * 8,
              q_lds + (size_t)(i * 512 + (tid & ~63)) * 8);
  }
  __syncthreads();

  f32x4 sacc[4][8];
#pragma unroll
  for (int nf = 0; nf < 4; ++nf)
#pragma unroll
    for (int g = 0; g < 8; ++g) sacc[nf][g] = (f32x4){0.f, 0.f, 0.f, 0.f};

  const u16* kp = Kb + (boff + mh * 1024 + mt * 128 + w * 16 + l15) * 1024 + quad * 8;

  // 3-deep K-fragment ring: load g and g+1 up front, prefetch g+2 each iter.
  bf16x8 kf[3][4];
#pragma unroll
  for (int ks = 0; ks < 4; ++ks) kf[0][ks] = *(const bf16x8*)(kp + 0 * 128 + ks * 32);
#pragma unroll
  for (int ks = 0; ks < 4; ++ks) kf[1][ks] = *(const bf16x8*)(kp + 1 * 128 + ks * 32);

#pragma unroll
  for (int g = 0; g < 8; ++g) {
    if (g < 6) {
#pragma unroll
      for (int ks = 0; ks < 4; ++ks)
        kf[(g + 2) % 3][ks] = *(const bf16x8*)(kp + (g + 2) * 128 + ks * 32);
    }
    __builtin_amdgcn_s_setprio(1);
#pragma unroll
    for (int ks = 0; ks < 4; ++ks) {
      const int kc = g * 16 + ks * 4 + quad;   // logical h-chunk
#pragma unroll
      for (int nf = 0; nf < 4; ++nf) {
        const int row = nf * 16 + l15;
        bf16x8 qf = *(const bf16x8*)&q_lds[row * 1024 + ((kc ^ (row & 7)) << 3)];
        sacc[nf][g] = MFMA16(kf[g % 3][ks], qf, sacc[nf][g]);  // D[m][n]
      }
    }
    __builtin_amdgcn_s_setprio(0);
  }
  // softmax over g (register-local)
#pragma unroll
  for (int nf = 0; nf < 4; ++nf)
#pragma unroll
    for (int r = 0; r < 4; ++r) {
      float s[8];
#pragma unroll
      for (int g = 0; g < 8; ++g) s[g] = sacc[nf][g][r] * 0.03125f;
      float mx = s[0];
#pragma unroll
      for (int g = 1; g < 8; ++g) mx = fmaxf(mx, s[g]);
      float sum = 0.f;
#pragma unroll
      for (int g = 0; g < 8; ++g) { s[g] = __expf(s[g] - mx); sum += s[g]; }
      const float rs = 1.0f / sum;
#pragma unroll
      for (int g = 0; g < 8; ++g) sacc[nf][g][r] = s[g] * rs;
    }
  // store Pt[b][g][mt][n][128m] non-temporally (read once by k_pv, via L3)
  const int mloc = w * 16 + quad * 4;
#pragma unroll
  for (int g = 0; g < 8; ++g) {
    const size_t gm = ((size_t)(bcoord * 8 + g) * 8 + mt) * 2048;
#pragma unroll
    for (int nf = 0; nf < 4; ++nf) {
      s16x4 pk;
#pragma unroll
      for (int r = 0; r < 4; ++r) pk[r] = (short)f2bf(sacc[nf][g][r]);
      __builtin_nontemporal_store(pk,
          (s16x4*)(Pt + (gm + (size_t)(nbase + nf * 16 + l15)) * 128 + mloc));
    }
  }
}

// ---------- kernel 6: PV GEMM (r1 form: 24 KB single buffer, no atomics) ----------
// grid 512 = 8g (XCD-pinned) x 32mt x 2b; 8 waves (2wr x 4wc); tile 64n x 128h.
// NT policy: Pt staging (8.4 MB/XCD streamed once) and out traffic bypass L2,
// so the reused Vt slice (512 KB/XCD) stays hot.
// mh==0 plain-stores, mh==1 load-add-store.
__global__ __launch_bounds__(512, 4) void k_pv(
    const u16* __restrict__ Pt, const u16* __restrict__ Vt,
    float* __restrict__ out, int mh) {
  __shared__ u16 a_lds[64 * 64];
  __shared__ u16 b_lds[128 * 64];
  const int tid = threadIdx.x;
  const int lane = tid & 63, wid = tid >> 6;
  const int l15 = lane & 15, quad = lane >> 4;
  const int wr = wid >> 2, wc = wid & 3;
  const int bx = blockIdx.x;
  const int g = bx & 7;
  const int mt = (bx >> 3) & 31;
  const int bcoord = bx >> 8;
  const int nbase = mt * 64;

  const u16* asrc = Pt + ((size_t)(bcoord * 8 + g) * 8 * 2048 + nbase) * 128;
  const u16* bsrc = Vt + (size_t)(bcoord * 8 + g) * 128 * 2048 + mh * 1024;

  f32x4 acc[2][2];
#pragma unroll
  for (int i = 0; i < 2; ++i)
#pragma unroll
    for (int j = 0; j < 2; ++j) acc[i][j] = (f32x4){0.f, 0.f, 0.f, 0.f};

  for (int kb = 0; kb < 16; ++kb) {
    __syncthreads();
    {  // stage A 64x64 (512 chunks, 1 per thread), NT (stream, no reuse)
      const int r = tid >> 3, pc = tid & 7;
      const int lc = pc ^ (r & 7);
      gload16nt(asrc + ((size_t)(kb >> 1) * 2048 + r) * 128 + (kb & 1) * 64 + lc * 8,
                a_lds + (size_t)(tid & ~63) * 8);
    }
    stage512(bsrc + kb * 64, 2048, b_lds, tid);
    __syncthreads();
#pragma unroll
    for (int ks = 0; ks < 2; ++ks) {
      const int kc = ks * 4 + quad;
      bf16x8 af[2], bfr[2];
#pragma unroll
      for (int mf = 0; mf < 2; ++mf) af[mf] = TILE_AT(a_lds, wr * 32 + mf * 16 + l15, kc);
#pragma unroll
      for (int nf = 0; nf < 2; ++nf) bfr[nf] = TILE_AT(b_lds, wc * 32 + nf * 16 + l15, kc);
#pragma unroll
      for (int mf = 0; mf < 2; ++mf)
#pragma unroll
        for (int nf = 0; nf < 2; ++nf)
          acc[mf][nf] = MFMA16(af[mf], bfr[nf], acc[mf][nf]);
    }
  }
#pragma unroll
  for (int mf = 0; mf < 2; ++mf)
#pragma unroll
    for (int nf = 0; nf < 2; ++nf)
#pragma unroll
      for (int r = 0; r < 4; ++r) {
        const int nrow = nbase + wr * 32 + mf * 16 + quad * 4 + r;
        const int col = g * 128 + wc * 32 + nf * 16 + l15;
        float* p = out + ((size_t)bcoord * 2048 + nrow) * 1024 + col;
        if (mh == 0) {
          __builtin_nontemporal_store(acc[mf][nf][r], p);
        } else {
          float prev = __builtin_nontemporal_load(p);
          __builtin_nontemporal_store(prev + acc[mf][nf][r], p);
        }
      }
}

extern "C" void kernel_launch(void* const* d_in, const int* in_sizes, int n_in,
                              void* d_out, int out_size, void* d_ws, size_t ws_size,
                              hipStream_t stream) {
  const float* hs = (const float*)d_in[0];
  const float* Wq = (const float*)d_in[1];
  const float* bq = (const float*)d_in[2];
  const float* Wk = (const float*)d_in[3];
  const float* bk = (const float*)d_in[4];
  const float* Wv = (const float*)d_in[5];
  const float* bv = (const float*)d_in[6];
  float* out = (float*)d_out;

  u16* ws = (u16*)d_ws;
  u16* hsb = ws;                   // 4096x1024
  u16* Wt  = ws + 4194304;         // 3 x 1024x1024 (j-major)
  u16* Qb  = ws + 7340032;         // [b][n][1024]
  u16* Kb  = ws + 11534336;        // [b][m][1024]
  u16* Vt  = ws + 15728640;        // [b][g][h][m] = [2][8][128][2048]
  u16* Pt  = ws + 19922944;        // [b][g][mt][n][128m] = [2][8][8][2048][128]

  k_prep<<<5120, 256, 0, stream>>>(hs, hsb, Wq, Wk, Wv, Wt);
  k_qkv<<<32 * 24, 256, 0, stream>>>(hsb, Wt, bq, bk, bv, Qb, Kb, Vt);
  for (int mh = 0; mh < 2; ++mh) {
    k_score<<<512, 512, 0, stream>>>(Qb, Kb, Pt, mh);
    k_pv<<<512, 512, 0, stream>>>(Pt, Vt, out, mh);
  }
}

// Round 11
// 236.334 us; speedup vs baseline: 1.9396x; 1.4483x over previous
//
#include <hip/hip_runtime.h>
#include <stdint.h>

typedef unsigned short u16;
typedef __attribute__((ext_vector_type(8))) short bf16x8;
typedef __attribute__((ext_vector_type(4))) short s16x4;
typedef __attribute__((ext_vector_type(4))) float f32x4;

#define MFMA16(a,b,c) __builtin_amdgcn_mfma_f32_16x16x32_bf16((a),(b),(c),0,0,0)

__device__ __forceinline__ u16 f2bf(float f) {
  union { float f; uint32_t u; } v; v.f = f;
  return (u16)((v.u + 0x7fffu + ((v.u >> 16) & 1u)) >> 16);
}

// async 16B global->LDS (lds dest = wave-uniform base + lane*16)
__device__ __forceinline__ void gload16(const void* g, void* l) {
  __builtin_amdgcn_global_load_lds((const __attribute__((address_space(1))) void*)g,
                                   (__attribute__((address_space(3))) void*)l, 16, 0, 0);
}

// Stage a 128x64 bf16 tile into lds[128*64] with chunk-xor swizzle.
// Physical chunk (r, pc) holds logical chunk (r, pc^(r&7)).
__device__ __forceinline__ void stage256(const u16* src, size_t stride, u16* lds, int tid) {
#pragma unroll
  for (int i = 0; i < 4; ++i) {
    const int L = i * 256 + tid;       // chunk 0..1023
    const int r = L >> 3, pc = L & 7;
    const int lc = pc ^ (r & 7);
    gload16(src + (size_t)r * stride + lc * 8, lds + (size_t)(i * 256 + (tid & ~63)) * 8);
  }
}
__device__ __forceinline__ void stage512(const u16* src, size_t stride, u16* lds, int tid) {
#pragma unroll
  for (int i = 0; i < 2; ++i) {
    const int L = i * 512 + tid;
    const int r = L >> 3, pc = L & 7;
    const int lc = pc ^ (r & 7);
    gload16(src + (size_t)r * stride + lc * 8, lds + (size_t)(i * 512 + (tid & ~63)) * 8);
  }
}
// read logical chunk kc of row from a swizzled (rows x 64) tile
#define TILE_AT(lds, row, kc) \
  (*(const bf16x8*)&(lds)[((((row) << 3) + ((kc) ^ ((row) & 7)))) << 3])

// ---------- kernel 1: prep = cast hidden_states + transpose 3 weights ----------
__global__ void k_prep(const float* __restrict__ hs, u16* __restrict__ hsb,
                       const float* __restrict__ Wq, const float* __restrict__ Wk,
                       const float* __restrict__ Wv, u16* __restrict__ Wt0) {
  __shared__ u16 tile[32][33];
  const int bx = blockIdx.x;
  if (bx < 2048) {
    const int idx = bx * 256 + threadIdx.x;      // exactly 524288 chunks
    const float4* s = (const float4*)hs + (size_t)idx * 2;
    float4 a = s[0], b = s[1];
    bf16x8 o;
    o[0] = (short)f2bf(a.x); o[1] = (short)f2bf(a.y);
    o[2] = (short)f2bf(a.z); o[3] = (short)f2bf(a.w);
    o[4] = (short)f2bf(b.x); o[5] = (short)f2bf(b.y);
    o[6] = (short)f2bf(b.z); o[7] = (short)f2bf(b.w);
    *(bf16x8*)(hsb + (size_t)idx * 8) = o;
    return;
  }
  const int bb = bx - 2048;
  const int widx = bb >> 10;
  const float* W = (widx == 0) ? Wq : ((widx == 1) ? Wk : Wv);
  u16* Wt = Wt0 + (size_t)widx * 1048576;
  const int bid = bb & 1023;
  int bd = bid >> 5, bj = bid & 31;
  int tx = threadIdx.x & 31, ty = threadIdx.x >> 5;
#pragma unroll
  for (int i = 0; i < 32; i += 8)
    tile[ty + i][tx] = f2bf(W[(size_t)(bd * 32 + ty + i) * 1024 + bj * 32 + tx]);
  __syncthreads();
#pragma unroll
  for (int i = 0; i < 32; i += 8)
    Wt[(size_t)(bj * 32 + ty + i) * 1024 + bd * 32 + tx] = tile[tx][ty + i];
}

// ---------- kernel 4: fused QKV GEMM (r1 form: single-buffer, 2 barriers/kb) ----------
__global__ __launch_bounds__(256, 2) void k_qkv(
    const u16* __restrict__ hsb, const u16* __restrict__ Wt,
    const float* __restrict__ bq, const float* __restrict__ bk, const float* __restrict__ bv,
    u16* __restrict__ Qb, u16* __restrict__ Kb, u16* __restrict__ Vt) {
  __shared__ u16 a_lds[128 * 64];
  __shared__ u16 b_lds[128 * 64];
  const int tid = threadIdx.x;
  const int lane = tid & 63, wid = tid >> 6;
  const int l15 = lane & 15, quad = lane >> 4;
  const int wr = wid >> 1, wc = wid & 1;
  const int bx = blockIdx.x & 31;
  const int by = blockIdx.x >> 5;
  const int Mbase = bx * 128;
  const int widx = by >> 3;               // 0=Q 1=K 2=V
  const int Nloc = (by & 7) * 128;

  f32x4 acc[4][4];
#pragma unroll
  for (int i = 0; i < 4; ++i)
#pragma unroll
    for (int j = 0; j < 4; ++j) acc[i][j] = (f32x4){0.f, 0.f, 0.f, 0.f};

  const u16* asrc = hsb + (size_t)Mbase * 1024;
  const u16* bsrc = Wt + (size_t)widx * 1048576 + (size_t)Nloc * 1024;

  for (int kb = 0; kb < 16; ++kb) {
    __syncthreads();
    stage256(asrc + kb * 64, 1024, a_lds, tid);
    stage256(bsrc + kb * 64, 1024, b_lds, tid);
    __syncthreads();
#pragma unroll
    for (int ks = 0; ks < 2; ++ks) {
      const int kc = ks * 4 + quad;
      bf16x8 af[4], bfr[4];
#pragma unroll
      for (int mt = 0; mt < 4; ++mt) af[mt] = TILE_AT(a_lds, wr * 64 + mt * 16 + l15, kc);
#pragma unroll
      for (int nt = 0; nt < 4; ++nt) bfr[nt] = TILE_AT(b_lds, wc * 64 + nt * 16 + l15, kc);
#pragma unroll
      for (int mt = 0; mt < 4; ++mt)
#pragma unroll
        for (int nt = 0; nt < 4; ++nt)
          acc[mt][nt] = MFMA16(af[mt], bfr[nt], acc[mt][nt]);
    }
  }
  const float* bias = (widx == 0) ? bq : ((widx == 1) ? bk : bv);
#pragma unroll
  for (int nt = 0; nt < 4; ++nt) {
    const int jloc = Nloc + wc * 64 + nt * 16 + l15;
    const float bias_v = bias[jloc];
#pragma unroll
    for (int mt = 0; mt < 4; ++mt) {
      const int Mr0 = Mbase + wr * 64 + mt * 16 + quad * 4;
      if (widx == 2) {
        const int b = Mr0 >> 11, mseq = Mr0 & 2047;
        const int g = jloc >> 7, h = jloc & 127;
        s16x4 pk;
#pragma unroll
        for (int r = 0; r < 4; ++r) pk[r] = (short)f2bf(acc[mt][nt][r] + bias_v);
        *(s16x4*)(Vt + (((size_t)b * 8 + g) * 128 + h) * 2048 + mseq) = pk;
      } else {
        u16* dst = (widx == 0) ? Qb : Kb;
#pragma unroll
        for (int r = 0; r < 4; ++r)
          dst[(size_t)(Mr0 + r) * 1024 + jloc] = f2bf(acc[mt][nt][r] + bias_v);
      }
    }
  }
}

// ---------- kernel 5: scores + softmax-over-g -> Pt[b][g][mt][n][128m] ----------
// r8 structure EXACTLY (1 block/CU, XCD-pinned mt, nf=4, 3-deep kf ring;
// occupancy/merge/NT attempts all regressed: r2/r6/r9/r10).
// ONLY change vs r8: kf[0]/kf[1] loads hoisted ABOVE the Q-stage barrier --
// their addresses don't depend on LDS, and the barrier's vmcnt(0) drain
// means they complete during the Q-stage for free (K-chain cold start hidden).
__global__ __launch_bounds__(512, 2) void k_score(
    const u16* __restrict__ Qb, const u16* __restrict__ Kb,
    u16* __restrict__ Pt, int mh) {
  __shared__ u16 q_lds[64 * 1024];  // 128 KB, 16B chunks xor-swizzled by (row&7)
  const int tid = threadIdx.x;
  const int w = tid >> 6;
  const int lane = tid & 63;
  const int l15 = lane & 15, quad = lane >> 4;
  const int bx = blockIdx.x;
  const int mt = bx & 7;                 // XCD-pinned m-chunk (128 m rows)
  const int nt = (bx >> 3) & 31;
  const int bcoord = bx >> 8;
  const int nbase = nt * 64;
  const size_t boff = (size_t)bcoord * 2048;

  // stage Q tile 64 x 1024 (8192 16B-chunks, 16 per thread), swizzled source
#pragma unroll
  for (int i = 0; i < 16; ++i) {
    const int idx = i * 512 + tid;
    const int r = idx >> 7, pc = idx & 127;
    const int lc = pc ^ (r & 7);
    gload16(Qb + (boff + nbase + r) * 1024 + lc * 8,
            q_lds + (size_t)(i * 512 + (tid & ~63)) * 8);
  }

  const u16* kp = Kb + (boff + mh * 1024 + mt * 128 + w * 16 + l15) * 1024 + quad * 8;

  // K-chain cold start: issue ring slots 0 and 1 BEFORE the barrier so they
  // land during the Q-stage drain (addresses are LDS-independent).
  bf16x8 kf[3][4];
#pragma unroll
  for (int ks = 0; ks < 4; ++ks) kf[0][ks] = *(const bf16x8*)(kp + 0 * 128 + ks * 32);
#pragma unroll
  for (int ks = 0; ks < 4; ++ks) kf[1][ks] = *(const bf16x8*)(kp + 1 * 128 + ks * 32);

  __syncthreads();

  f32x4 sacc[4][8];
#pragma unroll
  for (int nf = 0; nf < 4; ++nf)
#pragma unroll
    for (int g = 0; g < 8; ++g) sacc[nf][g] = (f32x4){0.f, 0.f, 0.f, 0.f};

#pragma unroll
  for (int g = 0; g < 8; ++g) {
    if (g < 6) {
#pragma unroll
      for (int ks = 0; ks < 4; ++ks)
        kf[(g + 2) % 3][ks] = *(const bf16x8*)(kp + (g + 2) * 128 + ks * 32);
    }
    __builtin_amdgcn_s_setprio(1);
#pragma unroll
    for (int ks = 0; ks < 4; ++ks) {
      const int kc = g * 16 + ks * 4 + quad;   // logical h-chunk
#pragma unroll
      for (int nf = 0; nf < 4; ++nf) {
        const int row = nf * 16 + l15;
        bf16x8 qf = *(const bf16x8*)&q_lds[row * 1024 + ((kc ^ (row & 7)) << 3)];
        sacc[nf][g] = MFMA16(kf[g % 3][ks], qf, sacc[nf][g]);  // D[m][n]
      }
    }
    __builtin_amdgcn_s_setprio(0);
  }
  // softmax over g (register-local)
#pragma unroll
  for (int nf = 0; nf < 4; ++nf)
#pragma unroll
    for (int r = 0; r < 4; ++r) {
      float s[8];
#pragma unroll
      for (int g = 0; g < 8; ++g) s[g] = sacc[nf][g][r] * 0.03125f;
      float mx = s[0];
#pragma unroll
      for (int g = 1; g < 8; ++g) mx = fmaxf(mx, s[g]);
      float sum = 0.f;
#pragma unroll
      for (int g = 0; g < 8; ++g) { s[g] = __expf(s[g] - mx); sum += s[g]; }
      const float rs = 1.0f / sum;
#pragma unroll
      for (int g = 0; g < 8; ++g) sacc[nf][g][r] = s[g] * rs;
    }
  // store Pt[b][g][mt][n][128m], m contiguous per lane (s16x4 along m)
  const int mloc = w * 16 + quad * 4;
#pragma unroll
  for (int g = 0; g < 8; ++g) {
    const size_t gm = ((size_t)(bcoord * 8 + g) * 8 + mt) * 2048;
#pragma unroll
    for (int nf = 0; nf < 4; ++nf) {
      s16x4 pk;
#pragma unroll
      for (int r = 0; r < 4; ++r) pk[r] = (short)f2bf(sacc[nf][g][r]);
      *(s16x4*)(Pt + (gm + (size_t)(nbase + nf * 16 + l15)) * 128 + mloc) = pk;
    }
  }
}

// ---------- kernel 6: PV GEMM (r1 form: 24 KB single buffer, no atomics) ----------
// grid 512 = 8g (XCD-pinned) x 32mt x 2b; 8 waves (2wr x 4wc); tile 64n x 128h.
// mh==0 plain-stores, mh==1 load-add-store.
__global__ __launch_bounds__(512, 4) void k_pv(
    const u16* __restrict__ Pt, const u16* __restrict__ Vt,
    float* __restrict__ out, int mh) {
  __shared__ u16 a_lds[64 * 64];
  __shared__ u16 b_lds[128 * 64];
  const int tid = threadIdx.x;
  const int lane = tid & 63, wid = tid >> 6;
  const int l15 = lane & 15, quad = lane >> 4;
  const int wr = wid >> 2, wc = wid & 3;
  const int bx = blockIdx.x;
  const int g = bx & 7;
  const int mt = (bx >> 3) & 31;
  const int bcoord = bx >> 8;
  const int nbase = mt * 64;

  const u16* asrc = Pt + ((size_t)(bcoord * 8 + g) * 8 * 2048 + nbase) * 128;
  const u16* bsrc = Vt + (size_t)(bcoord * 8 + g) * 128 * 2048 + mh * 1024;

  f32x4 acc[2][2];
#pragma unroll
  for (int i = 0; i < 2; ++i)
#pragma unroll
    for (int j = 0; j < 2; ++j) acc[i][j] = (f32x4){0.f, 0.f, 0.f, 0.f};

  for (int kb = 0; kb < 16; ++kb) {
    __syncthreads();
    {  // stage A 64x64 (512 chunks, 1 per thread)
      const int r = tid >> 3, pc = tid & 7;
      const int lc = pc ^ (r & 7);
      gload16(asrc + ((size_t)(kb >> 1) * 2048 + r) * 128 + (kb & 1) * 64 + lc * 8,
              a_lds + (size_t)(tid & ~63) * 8);
    }
    stage512(bsrc + kb * 64, 2048, b_lds, tid);
    __syncthreads();
#pragma unroll
    for (int ks = 0; ks < 2; ++ks) {
      const int kc = ks * 4 + quad;
      bf16x8 af[2], bfr[2];
#pragma unroll
      for (int mf = 0; mf < 2; ++mf) af[mf] = TILE_AT(a_lds, wr * 32 + mf * 16 + l15, kc);
#pragma unroll
      for (int nf = 0; nf < 2; ++nf) bfr[nf] = TILE_AT(b_lds, wc * 32 + nf * 16 + l15, kc);
#pragma unroll
      for (int mf = 0; mf < 2; ++mf)
#pragma unroll
        for (int nf = 0; nf < 2; ++nf)
          acc[mf][nf] = MFMA16(af[mf], bfr[nf], acc[mf][nf]);
    }
  }
#pragma unroll
  for (int mf = 0; mf < 2; ++mf)
#pragma unroll
    for (int nf = 0; nf < 2; ++nf)
#pragma unroll
      for (int r = 0; r < 4; ++r) {
        const int nrow = nbase + wr * 32 + mf * 16 + quad * 4 + r;
        const int col = g * 128 + wc * 32 + nf * 16 + l15;
        float* p = out + ((size_t)bcoord * 2048 + nrow) * 1024 + col;
        if (mh == 0) *p = acc[mf][nf][r];
        else        *p += acc[mf][nf][r];
      }
}

extern "C" void kernel_launch(void* const* d_in, const int* in_sizes, int n_in,
                              void* d_out, int out_size, void* d_ws, size_t ws_size,
                              hipStream_t stream) {
  const float* hs = (const float*)d_in[0];
  const float* Wq = (const float*)d_in[1];
  const float* bq = (const float*)d_in[2];
  const float* Wk = (const float*)d_in[3];
  const float* bk = (const float*)d_in[4];
  const float* Wv = (const float*)d_in[5];
  const float* bv = (const float*)d_in[6];
  float* out = (float*)d_out;

  u16* ws = (u16*)d_ws;
  u16* hsb = ws;                   // 4096x1024
  u16* Wt  = ws + 4194304;         // 3 x 1024x1024 (j-major)
  u16* Qb  = ws + 7340032;         // [b][n][1024]
  u16* Kb  = ws + 11534336;        // [b][m][1024]
  u16* Vt  = ws + 15728640;        // [b][g][h][m] = [2][8][128][2048]
  u16* Pt  = ws + 19922944;        // [b][g][mt][n][128m] = [2][8][8][2048][128]

  k_prep<<<5120, 256, 0, stream>>>(hs, hsb, Wq, Wk, Wv, Wt);
  k_qkv<<<32 * 24, 256, 0, stream>>>(hsb, Wt, bq, bk, bv, Qb, Kb, Vt);
  for (int mh = 0; mh < 2; ++mh) {
    k_score<<<512, 512, 0, stream>>>(Qb, Kb, Pt, mh);
    k_pv<<<512, 512, 0, stream>>>(Pt, Vt, out, mh);
  }
}

// Round 12
// 223.389 us; speedup vs baseline: 2.0520x; 1.0579x over previous
//
#include <hip/hip_runtime.h>
#include <stdint.h>

typedef unsigned short u16;
typedef __attribute__((ext_vector_type(8))) short bf16x8;
typedef __attribute__((ext_vector_type(4))) short s16x4;
typedef __attribute__((ext_vector_type(4))) float f32x4;

#define MFMA16(a,b,c) __builtin_amdgcn_mfma_f32_16x16x32_bf16((a),(b),(c),0,0,0)

__device__ __forceinline__ u16 f2bf(float f) {
  union { float f; uint32_t u; } v; v.f = f;
  return (u16)((v.u + 0x7fffu + ((v.u >> 16) & 1u)) >> 16);
}

// async 16B global->LDS (lds dest = wave-uniform base + lane*16)
__device__ __forceinline__ void gload16(const void* g, void* l) {
  __builtin_amdgcn_global_load_lds((const __attribute__((address_space(1))) void*)g,
                                   (__attribute__((address_space(3))) void*)l, 16, 0, 0);
}

// Stage a 128x64 bf16 tile into lds[128*64] with chunk-xor swizzle.
// Physical chunk (r, pc) holds logical chunk (r, pc^(r&7)).
__device__ __forceinline__ void stage256(const u16* src, size_t stride, u16* lds, int tid) {
#pragma unroll
  for (int i = 0; i < 4; ++i) {
    const int L = i * 256 + tid;       // chunk 0..1023
    const int r = L >> 3, pc = L & 7;
    const int lc = pc ^ (r & 7);
    gload16(src + (size_t)r * stride + lc * 8, lds + (size_t)(i * 256 + (tid & ~63)) * 8);
  }
}
__device__ __forceinline__ void stage512(const u16* src, size_t stride, u16* lds, int tid) {
#pragma unroll
  for (int i = 0; i < 2; ++i) {
    const int L = i * 512 + tid;
    const int r = L >> 3, pc = L & 7;
    const int lc = pc ^ (r & 7);
    gload16(src + (size_t)r * stride + lc * 8, lds + (size_t)(i * 512 + (tid & ~63)) * 8);
  }
}
// read logical chunk kc of row from a swizzled (rows x 64) tile
#define TILE_AT(lds, row, kc) \
  (*(const bf16x8*)&(lds)[((((row) << 3) + ((kc) ^ ((row) & 7)))) << 3])

// ---------- kernel 1: prep = cast hidden_states + transpose 3 weights ----------
__global__ void k_prep(const float* __restrict__ hs, u16* __restrict__ hsb,
                       const float* __restrict__ Wq, const float* __restrict__ Wk,
                       const float* __restrict__ Wv, u16* __restrict__ Wt0) {
  __shared__ u16 tile[32][33];
  const int bx = blockIdx.x;
  if (bx < 2048) {
    const int idx = bx * 256 + threadIdx.x;      // exactly 524288 chunks
    const float4* s = (const float4*)hs + (size_t)idx * 2;
    float4 a = s[0], b = s[1];
    bf16x8 o;
    o[0] = (short)f2bf(a.x); o[1] = (short)f2bf(a.y);
    o[2] = (short)f2bf(a.z); o[3] = (short)f2bf(a.w);
    o[4] = (short)f2bf(b.x); o[5] = (short)f2bf(b.y);
    o[6] = (short)f2bf(b.z); o[7] = (short)f2bf(b.w);
    *(bf16x8*)(hsb + (size_t)idx * 8) = o;
    return;
  }
  const int bb = bx - 2048;
  const int widx = bb >> 10;
  const float* W = (widx == 0) ? Wq : ((widx == 1) ? Wk : Wv);
  u16* Wt = Wt0 + (size_t)widx * 1048576;
  const int bid = bb & 1023;
  int bd = bid >> 5, bj = bid & 31;
  int tx = threadIdx.x & 31, ty = threadIdx.x >> 5;
#pragma unroll
  for (int i = 0; i < 32; i += 8)
    tile[ty + i][tx] = f2bf(W[(size_t)(bd * 32 + ty + i) * 1024 + bj * 32 + tx]);
  __syncthreads();
#pragma unroll
  for (int i = 0; i < 32; i += 8)
    Wt[(size_t)(bj * 32 + ty + i) * 1024 + bd * 32 + tx] = tile[tx][ty + i];
}

// ---------- kernel 4: fused QKV GEMM (r1 form: single-buffer, 2 barriers/kb) ----------
__global__ __launch_bounds__(256, 2) void k_qkv(
    const u16* __restrict__ hsb, const u16* __restrict__ Wt,
    const float* __restrict__ bq, const float* __restrict__ bk, const float* __restrict__ bv,
    u16* __restrict__ Qb, u16* __restrict__ Kb, u16* __restrict__ Vt) {
  __shared__ u16 a_lds[128 * 64];
  __shared__ u16 b_lds[128 * 64];
  const int tid = threadIdx.x;
  const int lane = tid & 63, wid = tid >> 6;
  const int l15 = lane & 15, quad = lane >> 4;
  const int wr = wid >> 1, wc = wid & 1;
  const int bx = blockIdx.x & 31;
  const int by = blockIdx.x >> 5;
  const int Mbase = bx * 128;
  const int widx = by >> 3;               // 0=Q 1=K 2=V
  const int Nloc = (by & 7) * 128;

  f32x4 acc[4][4];
#pragma unroll
  for (int i = 0; i < 4; ++i)
#pragma unroll
    for (int j = 0; j < 4; ++j) acc[i][j] = (f32x4){0.f, 0.f, 0.f, 0.f};

  const u16* asrc = hsb + (size_t)Mbase * 1024;
  const u16* bsrc = Wt + (size_t)widx * 1048576 + (size_t)Nloc * 1024;

  for (int kb = 0; kb < 16; ++kb) {
    __syncthreads();
    stage256(asrc + kb * 64, 1024, a_lds, tid);
    stage256(bsrc + kb * 64, 1024, b_lds, tid);
    __syncthreads();
#pragma unroll
    for (int ks = 0; ks < 2; ++ks) {
      const int kc = ks * 4 + quad;
      bf16x8 af[4], bfr[4];
#pragma unroll
      for (int mt = 0; mt < 4; ++mt) af[mt] = TILE_AT(a_lds, wr * 64 + mt * 16 + l15, kc);
#pragma unroll
      for (int nt = 0; nt < 4; ++nt) bfr[nt] = TILE_AT(b_lds, wc * 64 + nt * 16 + l15, kc);
#pragma unroll
      for (int mt = 0; mt < 4; ++mt)
#pragma unroll
        for (int nt = 0; nt < 4; ++nt)
          acc[mt][nt] = MFMA16(af[mt], bfr[nt], acc[mt][nt]);
    }
  }
  const float* bias = (widx == 0) ? bq : ((widx == 1) ? bk : bv);
#pragma unroll
  for (int nt = 0; nt < 4; ++nt) {
    const int jloc = Nloc + wc * 64 + nt * 16 + l15;
    const float bias_v = bias[jloc];
#pragma unroll
    for (int mt = 0; mt < 4; ++mt) {
      const int Mr0 = Mbase + wr * 64 + mt * 16 + quad * 4;
      if (widx == 2) {
        const int b = Mr0 >> 11, mseq = Mr0 & 2047;
        const int g = jloc >> 7, h = jloc & 127;
        s16x4 pk;
#pragma unroll
        for (int r = 0; r < 4; ++r) pk[r] = (short)f2bf(acc[mt][nt][r] + bias_v);
        *(s16x4*)(Vt + (((size_t)b * 8 + g) * 128 + h) * 2048 + mseq) = pk;
      } else {
        u16* dst = (widx == 0) ? Qb : Kb;
#pragma unroll
        for (int r = 0; r < 4; ++r)
          dst[(size_t)(Mr0 + r) * 1024 + jloc] = f2bf(acc[mt][nt][r] + bias_v);
      }
    }
  }
}

// ---------- kernel 5: scores + softmax-over-g -> Pt[b][g][mt][n][128m] ----------
// FROZEN at the r11 form (r8 + kf cold-start hoist; 46.9 us measured).
// 1 block/CU, XCD-pinned mt, nf=4, 3-deep kf ring. 11 rounds of evidence:
// occupancy is info-theoretically capped (128 scores/lane), and every
// footprint/policy change fell off the L2 ledge (r2/r6/r9/r10).
__global__ __launch_bounds__(512, 2) void k_score(
    const u16* __restrict__ Qb, const u16* __restrict__ Kb,
    u16* __restrict__ Pt, int mh) {
  __shared__ u16 q_lds[64 * 1024];  // 128 KB, 16B chunks xor-swizzled by (row&7)
  const int tid = threadIdx.x;
  const int w = tid >> 6;
  const int lane = tid & 63;
  const int l15 = lane & 15, quad = lane >> 4;
  const int bx = blockIdx.x;
  const int mt = bx & 7;                 // XCD-pinned m-chunk (128 m rows)
  const int nt = (bx >> 3) & 31;
  const int bcoord = bx >> 8;
  const int nbase = nt * 64;
  const size_t boff = (size_t)bcoord * 2048;

  // stage Q tile 64 x 1024 (8192 16B-chunks, 16 per thread), swizzled source
#pragma unroll
  for (int i = 0; i < 16; ++i) {
    const int idx = i * 512 + tid;
    const int r = idx >> 7, pc = idx & 127;
    const int lc = pc ^ (r & 7);
    gload16(Qb + (boff + nbase + r) * 1024 + lc * 8,
            q_lds + (size_t)(i * 512 + (tid & ~63)) * 8);
  }

  const u16* kp = Kb + (boff + mh * 1024 + mt * 128 + w * 16 + l15) * 1024 + quad * 8;

  // K-chain cold start: issue ring slots 0 and 1 BEFORE the barrier so they
  // land during the Q-stage drain (addresses are LDS-independent).
  bf16x8 kf[3][4];
#pragma unroll
  for (int ks = 0; ks < 4; ++ks) kf[0][ks] = *(const bf16x8*)(kp + 0 * 128 + ks * 32);
#pragma unroll
  for (int ks = 0; ks < 4; ++ks) kf[1][ks] = *(const bf16x8*)(kp + 1 * 128 + ks * 32);

  __syncthreads();

  f32x4 sacc[4][8];
#pragma unroll
  for (int nf = 0; nf < 4; ++nf)
#pragma unroll
    for (int g = 0; g < 8; ++g) sacc[nf][g] = (f32x4){0.f, 0.f, 0.f, 0.f};

#pragma unroll
  for (int g = 0; g < 8; ++g) {
    if (g < 6) {
#pragma unroll
      for (int ks = 0; ks < 4; ++ks)
        kf[(g + 2) % 3][ks] = *(const bf16x8*)(kp + (g + 2) * 128 + ks * 32);
    }
    __builtin_amdgcn_s_setprio(1);
#pragma unroll
    for (int ks = 0; ks < 4; ++ks) {
      const int kc = g * 16 + ks * 4 + quad;   // logical h-chunk
#pragma unroll
      for (int nf = 0; nf < 4; ++nf) {
        const int row = nf * 16 + l15;
        bf16x8 qf = *(const bf16x8*)&q_lds[row * 1024 + ((kc ^ (row & 7)) << 3)];
        sacc[nf][g] = MFMA16(kf[g % 3][ks], qf, sacc[nf][g]);  // D[m][n]
      }
    }
    __builtin_amdgcn_s_setprio(0);
  }
  // softmax over g (register-local)
#pragma unroll
  for (int nf = 0; nf < 4; ++nf)
#pragma unroll
    for (int r = 0; r < 4; ++r) {
      float s[8];
#pragma unroll
      for (int g = 0; g < 8; ++g) s[g] = sacc[nf][g][r] * 0.03125f;
      float mx = s[0];
#pragma unroll
      for (int g = 1; g < 8; ++g) mx = fmaxf(mx, s[g]);
      float sum = 0.f;
#pragma unroll
      for (int g = 0; g < 8; ++g) { s[g] = __expf(s[g] - mx); sum += s[g]; }
      const float rs = 1.0f / sum;
#pragma unroll
      for (int g = 0; g < 8; ++g) sacc[nf][g][r] = s[g] * rs;
    }
  // store Pt[b][g][mt][n][128m], m contiguous per lane (s16x4 along m)
  const int mloc = w * 16 + quad * 4;
#pragma unroll
  for (int g = 0; g < 8; ++g) {
    const size_t gm = ((size_t)(bcoord * 8 + g) * 8 + mt) * 2048;
#pragma unroll
    for (int nf = 0; nf < 4; ++nf) {
      s16x4 pk;
#pragma unroll
      for (int r = 0; r < 4; ++r) pk[r] = (short)f2bf(sacc[nf][g][r]);
      *(s16x4*)(Pt + (gm + (size_t)(nbase + nf * 16 + l15)) * 128 + mloc) = pk;
    }
  }
}

// ---------- kernel 6a: merged PV GEMM over BOTH m-halves, out stored once ----
// r1's proven 24 KB single-buffer schedule, kb 0..31 (kb>>4 selects the Pt
// buffer and the Vt column half). Eliminates the mh=1 dispatch's 16 MB
// read-modify-write of out and one launch. Per-XCD reuse set: two Vt
// half-slices = 1 MB << 4 MB L2 (not the r6/r9 write-footprint failure mode).
__global__ __launch_bounds__(512, 4) void k_pv2(
    const u16* __restrict__ Pt0, const u16* __restrict__ Pt1,
    const u16* __restrict__ Vt, float* __restrict__ out) {
  __shared__ u16 a_lds[64 * 64];
  __shared__ u16 b_lds[128 * 64];
  const int tid = threadIdx.x;
  const int lane = tid & 63, wid = tid >> 6;
  const int l15 = lane & 15, quad = lane >> 4;
  const int wr = wid >> 2, wc = wid & 3;
  const int bx = blockIdx.x;
  const int g = bx & 7;
  const int mt = (bx >> 3) & 31;
  const int bcoord = bx >> 8;
  const int nbase = mt * 64;

  const size_t aoff = ((size_t)(bcoord * 8 + g) * 8 * 2048 + nbase) * 128;
  const u16* bsrcg = Vt + (size_t)(bcoord * 8 + g) * 128 * 2048;

  f32x4 acc[2][2];
#pragma unroll
  for (int i = 0; i < 2; ++i)
#pragma unroll
    for (int j = 0; j < 2; ++j) acc[i][j] = (f32x4){0.f, 0.f, 0.f, 0.f};

  for (int kb = 0; kb < 32; ++kb) {
    const int half = kb >> 4, kbl = kb & 15;
    const u16* asrc = (half ? Pt1 : Pt0) + aoff;
    const u16* bsrc = bsrcg + half * 1024;
    __syncthreads();
    {  // stage A 64x64 (512 chunks, 1 per thread)
      const int r = tid >> 3, pc = tid & 7;
      const int lc = pc ^ (r & 7);
      gload16(asrc + ((size_t)(kbl >> 1) * 2048 + r) * 128 + (kbl & 1) * 64 + lc * 8,
              a_lds + (size_t)(tid & ~63) * 8);
    }
    stage512(bsrc + kbl * 64, 2048, b_lds, tid);
    __syncthreads();
#pragma unroll
    for (int ks = 0; ks < 2; ++ks) {
      const int kc = ks * 4 + quad;
      bf16x8 af[2], bfr[2];
#pragma unroll
      for (int mf = 0; mf < 2; ++mf) af[mf] = TILE_AT(a_lds, wr * 32 + mf * 16 + l15, kc);
#pragma unroll
      for (int nf = 0; nf < 2; ++nf) bfr[nf] = TILE_AT(b_lds, wc * 32 + nf * 16 + l15, kc);
#pragma unroll
      for (int mf = 0; mf < 2; ++mf)
#pragma unroll
        for (int nf = 0; nf < 2; ++nf)
          acc[mf][nf] = MFMA16(af[mf], bfr[nf], acc[mf][nf]);
    }
  }
#pragma unroll
  for (int mf = 0; mf < 2; ++mf)
#pragma unroll
    for (int nf = 0; nf < 2; ++nf)
#pragma unroll
      for (int r = 0; r < 4; ++r) {
        const int nrow = nbase + wr * 32 + mf * 16 + quad * 4 + r;
        const int col = g * 128 + wc * 32 + nf * 16 + l15;
        out[((size_t)bcoord * 2048 + nrow) * 1024 + col] = acc[mf][nf][r];
      }
}

// ---------- kernel 6b: fallback per-mh PV (r8 form) for small workspace ----
__global__ __launch_bounds__(512, 4) void k_pv(
    const u16* __restrict__ Pt, const u16* __restrict__ Vt,
    float* __restrict__ out, int mh) {
  __shared__ u16 a_lds[64 * 64];
  __shared__ u16 b_lds[128 * 64];
  const int tid = threadIdx.x;
  const int lane = tid & 63, wid = tid >> 6;
  const int l15 = lane & 15, quad = lane >> 4;
  const int wr = wid >> 2, wc = wid & 3;
  const int bx = blockIdx.x;
  const int g = bx & 7;
  const int mt = (bx >> 3) & 31;
  const int bcoord = bx >> 8;
  const int nbase = mt * 64;

  const u16* asrc = Pt + ((size_t)(bcoord * 8 + g) * 8 * 2048 + nbase) * 128;
  const u16* bsrc = Vt + (size_t)(bcoord * 8 + g) * 128 * 2048 + mh * 1024;

  f32x4 acc[2][2];
#pragma unroll
  for (int i = 0; i < 2; ++i)
#pragma unroll
    for (int j = 0; j < 2; ++j) acc[i][j] = (f32x4){0.f, 0.f, 0.f, 0.f};

  for (int kb = 0; kb < 16; ++kb) {
    __syncthreads();
    {
      const int r = tid >> 3, pc = tid & 7;
      const int lc = pc ^ (r & 7);
      gload16(asrc + ((size_t)(kb >> 1) * 2048 + r) * 128 + (kb & 1) * 64 + lc * 8,
              a_lds + (size_t)(tid & ~63) * 8);
    }
    stage512(bsrc + kb * 64, 2048, b_lds, tid);
    __syncthreads();
#pragma unroll
    for (int ks = 0; ks < 2; ++ks) {
      const int kc = ks * 4 + quad;
      bf16x8 af[2], bfr[2];
#pragma unroll
      for (int mf = 0; mf < 2; ++mf) af[mf] = TILE_AT(a_lds, wr * 32 + mf * 16 + l15, kc);
#pragma unroll
      for (int nf = 0; nf < 2; ++nf) bfr[nf] = TILE_AT(b_lds, wc * 32 + nf * 16 + l15, kc);
#pragma unroll
      for (int mf = 0; mf < 2; ++mf)
#pragma unroll
        for (int nf = 0; nf < 2; ++nf)
          acc[mf][nf] = MFMA16(af[mf], bfr[nf], acc[mf][nf]);
    }
  }
#pragma unroll
  for (int mf = 0; mf < 2; ++mf)
#pragma unroll
    for (int nf = 0; nf < 2; ++nf)
#pragma unroll
      for (int r = 0; r < 4; ++r) {
        const int nrow = nbase + wr * 32 + mf * 16 + quad * 4 + r;
        const int col = g * 128 + wc * 32 + nf * 16 + l15;
        float* p = out + ((size_t)bcoord * 2048 + nrow) * 1024 + col;
        if (mh == 0) *p = acc[mf][nf][r];
        else        *p += acc[mf][nf][r];
      }
}

extern "C" void kernel_launch(void* const* d_in, const int* in_sizes, int n_in,
                              void* d_out, int out_size, void* d_ws, size_t ws_size,
                              hipStream_t stream) {
  const float* hs = (const float*)d_in[0];
  const float* Wq = (const float*)d_in[1];
  const float* bq = (const float*)d_in[2];
  const float* Wk = (const float*)d_in[3];
  const float* bk = (const float*)d_in[4];
  const float* Wv = (const float*)d_in[5];
  const float* bv = (const float*)d_in[6];
  float* out = (float*)d_out;

  u16* ws = (u16*)d_ws;
  u16* hsb = ws;                   // 4096x1024
  u16* Wt  = ws + 4194304;         // 3 x 1024x1024 (j-major)
  u16* Qb  = ws + 7340032;         // [b][n][1024]
  u16* Kb  = ws + 11534336;        // [b][m][1024]
  u16* Vt  = ws + 15728640;        // [b][g][h][m] = [2][8][128][2048]
  u16* Pt0 = ws + 19922944;        // [b][g][mt][n][128m] = [2][8][8][2048][128]
  const size_t PT_ELEMS = 33554432ull;
  u16* Pt1 = Pt0 + PT_ELEMS;       // second m-half

  k_prep<<<5120, 256, 0, stream>>>(hs, hsb, Wq, Wk, Wv, Wt);
  k_qkv<<<32 * 24, 256, 0, stream>>>(hsb, Wt, bq, bk, bv, Qb, Kb, Vt);

  const size_t need_bytes = (19922944ull + 2 * PT_ELEMS) * 2;  // 174 MB
  if (ws_size >= need_bytes) {
    k_score<<<512, 512, 0, stream>>>(Qb, Kb, Pt0, 0);
    k_score<<<512, 512, 0, stream>>>(Qb, Kb, Pt1, 1);
    k_pv2<<<512, 512, 0, stream>>>(Pt0, Pt1, Vt, out);
  } else {
    for (int mh = 0; mh < 2; ++mh) {
      k_score<<<512, 512, 0, stream>>>(Qb, Kb, Pt0, mh);
      k_pv<<<512, 512, 0, stream>>>(Pt0, Vt, out, mh);
    }
  }
}